// Round 1
// baseline (6254.380 us; speedup 1.0000x reference)
//
#include <hip/hip_runtime.h>

// Encoder: D=4, L=16, C=64, H=W=128.
// Math simplifications (exact up to fp rounding):
//  * softmax_j(A_i + B_j + ba) == softmax_j(B_j): Q/Wq/bq/ba never needed.
//  * attn[i] identical for all i -> compute attnc[c,p] once, broadcast add.
//  * B = conv5(K-part) with K = Wk*h + bk  ==>  B = conv5(h, Weff),
//    Weff[ci][tap] = sum_co WaK[co][tap]*Wk[co][ci]; bk border term is
//    j-independent -> cancels in softmax too.

#define HW 16384      // 128*128
#define CHW 1048576   // 64*HW
#define LCHW 16777216 // 16*CHW

static __device__ __forceinline__ unsigned short f2bf(float f) {
  union { float f; unsigned int u; } v; v.f = f;
  unsigned int r = v.u + 0x7fffu + ((v.u >> 16) & 1u);
  return (unsigned short)(r >> 16);
}
static __device__ __forceinline__ float bf2f(unsigned short h) {
  union { unsigned int u; float f; } v; v.u = ((unsigned int)h) << 16;
  return v.f;
}

// ---- precompute Weff[d][ci][25] and W2T[d][o][c] ----
__global__ __launch_bounds__(256) void prep_kernel(
    const float* __restrict__ Wa, const float* __restrict__ Wk,
    const float* __restrict__ W2, float* __restrict__ weff,
    float* __restrict__ w2t) {
  int d = blockIdx.x, t = threadIdx.x;
  const float* WaK = Wa + ((size_t)d * 128 + 64) * 25;  // [co][tap]
  const float* Wkd = Wk + d * 4096;                     // [co][ci]
  for (int idx = t; idx < 1600; idx += 256) {
    int ci = idx / 25, tap = idx - ci * 25;
    float s = 0.f;
    for (int co = 0; co < 64; ++co)
      s = fmaf(WaK[co * 25 + tap], Wkd[co * 64 + ci], s);
    weff[d * 1600 + idx] = s;
  }
  const float* W2d = W2 + d * 8192;  // [c][o] o<128
  for (int idx = t; idx < 8192; idx += 256) {
    int o = idx >> 6, c = idx & 63;
    w2t[d * 8192 + idx] = W2d[c * 128 + o];
  }
}

// ---- per-frame sum / sumsq (atomic partial accumulation) ----
__global__ __launch_bounds__(256) void stats_kernel(
    const float* __restrict__ x, float* __restrict__ acc) {
  int tid = threadIdx.x;
  size_t base = (size_t)blockIdx.x * 4096;
  const float4* x4 = (const float4*)(x + base);
  float s = 0.f, q = 0.f;
#pragma unroll
  for (int k = 0; k < 4; ++k) {
    float4 v = x4[k * 256 + tid];
    s += v.x + v.y + v.z + v.w;
    q = fmaf(v.x, v.x, q); q = fmaf(v.y, v.y, q);
    q = fmaf(v.z, v.z, q); q = fmaf(v.w, v.w, q);
  }
#pragma unroll
  for (int off = 32; off > 0; off >>= 1) {
    s += __shfl_down(s, off);
    q += __shfl_down(q, off);
  }
  __shared__ float ls[4], lq[4];
  int wave = tid >> 6;
  if ((tid & 63) == 0) { ls[wave] = s; lq[wave] = q; }
  __syncthreads();
  if (tid == 0) {
    float S = ls[0] + ls[1] + ls[2] + ls[3];
    float Q = lq[0] + lq[1] + lq[2] + lq[3];
    int frame = blockIdx.x >> 8;  // 256 blocks per frame
    atomicAdd(&acc[frame * 2], S);
    atomicAdd(&acc[frame * 2 + 1], Q);
  }
}

// ---- finalize mu / rsqrt(var+eps); zero the other accumulator ----
__global__ __launch_bounds__(64) void sfinal_kernel(
    const float* __restrict__ acc, float* __restrict__ mur,
    float* __restrict__ accz) {
  int t = threadIdx.x;
  if (t < 16) {
    const float invN = 1.f / 1048576.f;
    float s = acc[2 * t], q = acc[2 * t + 1];
    float mu = s * invN;
    float var = q * invN - mu * mu;
    mur[2 * t] = mu;
    mur[2 * t + 1] = rsqrtf(var + 1e-5f);
  }
  if (t < 32) accz[t] = 0.f;
}

// ---- fused LN1 + V (1x1 conv) + B (5x5 conv with Weff) ----
__global__ __launch_bounds__(256) void vb_kernel(
    const float* __restrict__ x, const float* __restrict__ g,
    const float* __restrict__ bln, const float* __restrict__ Wv,
    const float* __restrict__ bv, const float* __restrict__ weff,
    const float* __restrict__ mur, float* __restrict__ V,
    float* __restrict__ Bout) {
  __shared__ unsigned short sh[64][400];  // bf16 h tile, 20x20 halo
  int l = blockIdx.z;
  int ty0 = blockIdx.y * 16, tx0 = blockIdx.x * 16;
  int tid = threadIdx.x;
  float mu = mur[2 * l], r = mur[2 * l + 1];
  for (int idx = tid; idx < 64 * 400; idx += 256) {
    int ci = idx / 400, q = idx - ci * 400;
    int row = q / 20, col = q - row * 20;
    int yy = ty0 + row - 2, xx = tx0 + col - 2;
    float v = 0.f;
    if (yy >= 0 && yy < 128 && xx >= 0 && xx < 128) {
      int pix = (yy << 7) + xx;
      size_t gi = (((size_t)l * 64 + ci) << 14) + pix;
      int li = (ci << 14) + pix;
      v = (x[gi] - mu) * r * g[li] + bln[li];
    }
    sh[ci][q] = f2bf(v);
  }
  __syncthreads();
  int ty = tid >> 4, tx = tid & 15;
  int pc = (ty + 2) * 20 + (tx + 2);
  float h[64];
#pragma unroll
  for (int ci = 0; ci < 64; ++ci) h[ci] = bf2f(sh[ci][pc]);
  int gy = ty0 + ty, gx = tx0 + tx;
  size_t opix = ((size_t)gy << 7) + gx;
  // V = Wv * h + bv   (weights via uniform scalar loads)
  for (int co = 0; co < 64; ++co) {
    const float* wr = Wv + (co << 6);
    float a0 = 0.f, a1 = 0.f, a2 = 0.f, a3 = 0.f;
#pragma unroll
    for (int ci = 0; ci < 64; ci += 4) {
      a0 = fmaf(wr[ci], h[ci], a0);
      a1 = fmaf(wr[ci + 1], h[ci + 1], a1);
      a2 = fmaf(wr[ci + 2], h[ci + 2], a2);
      a3 = fmaf(wr[ci + 3], h[ci + 3], a3);
    }
    V[(((size_t)l * 64 + co) << 14) + opix] = (a0 + a1) + (a2 + a3) + bv[co];
  }
  // B = sum_ci sum_tap Weff[ci][tap] * h[ci][y+dy-2][x+dx-2]
  float b0 = 0.f, b1_ = 0.f, b2_ = 0.f, b3 = 0.f;
  for (int ci = 0; ci < 64; ++ci) {
    const float* wrow = weff + ci * 25;
#pragma unroll
    for (int dy = 0; dy < 5; ++dy) {
      int rb = (ty + dy) * 20 + tx;
#pragma unroll
      for (int dx = 0; dx < 5; ++dx) {
        float hv = bf2f(sh[ci][rb + dx]);
        int k = dy * 5 + dx;
        float w = wrow[k];
        if ((k & 3) == 0) b0 = fmaf(w, hv, b0);
        else if ((k & 3) == 1) b1_ = fmaf(w, hv, b1_);
        else if ((k & 3) == 2) b2_ = fmaf(w, hv, b2_);
        else b3 = fmaf(w, hv, b3);
      }
    }
  }
  Bout[((size_t)l << 14) + opix] = (b0 + b1_) + (b2_ + b3);
}

// ---- attnc[c,p] = sum_j softmax_j(B[j,p]) * V[j,c,p] ----
__global__ __launch_bounds__(256) void attnc_kernel(
    const float* __restrict__ V, const float* __restrict__ B,
    float* __restrict__ attnc) {
  int gid = blockIdx.x * 256 + threadIdx.x;  // c*HW + p
  int p = gid & 16383, c = gid >> 14;
  float bj[16];
  float m = -1e30f;
#pragma unroll
  for (int j = 0; j < 16; ++j) {
    bj[j] = B[(j << 14) + p];
    m = fmaxf(m, bj[j]);
  }
  float sum = 0.f;
#pragma unroll
  for (int j = 0; j < 16; ++j) {
    bj[j] = __expf(bj[j] - m);
    sum += bj[j];
  }
  float inv = 1.f / sum;
  float a = 0.f;
#pragma unroll
  for (int j = 0; j < 16; ++j)
    a = fmaf(bj[j], V[(((size_t)j * 64 + c) << 14) + p], a);
  attnc[gid] = a * inv;
}

// ---- x[i,c,p] += attnc[c,p] for all frames i ----
__global__ __launch_bounds__(256) void update_kernel(
    float* __restrict__ x, const float* __restrict__ attnc) {
  int gid = blockIdx.x * 256 + threadIdx.x;  // c*HW + p
  float a = attnc[gid];
#pragma unroll
  for (int i = 0; i < 16; ++i) {
    size_t xi = ((size_t)i << 20) + gid;
    x[xi] += a;
  }
}

// ---- fused LN2 + FFN (W1->leaky->W2) + residual, all in registers ----
__global__ __launch_bounds__(256) void ffn_kernel(
    float* __restrict__ x, const float* __restrict__ g,
    const float* __restrict__ bln, const float* __restrict__ W1,
    const float* __restrict__ b1, const float* __restrict__ w2t,
    const float* __restrict__ b2, const float* __restrict__ mur) {
  int pg = blockIdx.x * 256 + threadIdx.x;  // l*HW + p
  int l = pg >> 14, p = pg & 16383;
  float mu = mur[2 * l], r = mur[2 * l + 1];
  float h[64], facc[64];
#pragma unroll
  for (int c = 0; c < 64; ++c) {
    size_t xi = ((size_t)l << 20) + (c << 14) + p;
    int li = (c << 14) + p;
    h[c] = (x[xi] - mu) * r * g[li] + bln[li];
    facc[c] = b2[c];
  }
  for (int o = 0; o < 128; ++o) {
    const float* wr = W1 + (o << 6);
    float t0 = 0.f, t1 = 0.f, t2 = 0.f, t3 = 0.f;
#pragma unroll
    for (int ci = 0; ci < 64; ci += 4) {
      t0 = fmaf(wr[ci], h[ci], t0);
      t1 = fmaf(wr[ci + 1], h[ci + 1], t1);
      t2 = fmaf(wr[ci + 2], h[ci + 2], t2);
      t3 = fmaf(wr[ci + 3], h[ci + 3], t3);
    }
    float f1 = (t0 + t1) + (t2 + t3) + b1[o];
    f1 = fmaxf(f1, 0.01f * f1);  // leaky relu, branchless
    const float* w2r = w2t + (o << 6);
#pragma unroll
    for (int c = 0; c < 64; ++c) facc[c] = fmaf(w2r[c], f1, facc[c]);
  }
#pragma unroll
  for (int c = 0; c < 64; ++c) {
    size_t xi = ((size_t)l << 20) + (c << 14) + p;
    x[xi] += facc[c];
  }
}

extern "C" void kernel_launch(void* const* d_in, const int* in_sizes, int n_in,
                              void* d_out, int out_size, void* d_ws,
                              size_t ws_size, hipStream_t stream) {
  const float* x_in = (const float*)d_in[0];
  const float* ln1_g = (const float*)d_in[1];
  const float* ln1_b = (const float*)d_in[2];
  // d_in[3]=Wq, d_in[4]=bq, d_in[6]=bk, d_in[10]=ba: cancel in softmax.
  const float* Wk = (const float*)d_in[5];
  const float* Wv = (const float*)d_in[7];
  const float* bv = (const float*)d_in[8];
  const float* Wa = (const float*)d_in[9];
  const float* ln2_g = (const float*)d_in[11];
  const float* ln2_b = (const float*)d_in[12];
  const float* W1 = (const float*)d_in[13];
  const float* b1 = (const float*)d_in[14];
  const float* W2 = (const float*)d_in[15];
  const float* b2 = (const float*)d_in[16];

  float* xbuf = (float*)d_out;
  float* ws = (float*)d_ws;
  float* V = ws;                    // 16777216 floats
  float* attn = ws + 16777216;      // 1048576
  float* Bbuf = ws + 17825792;      // 262144
  float* weff = ws + 18087936;      // 6400
  float* w2t = ws + 18094336;       // 32768
  float* acc1 = ws + 18127104;      // 32
  float* acc2 = ws + 18127136;      // 32
  float* mur1 = ws + 18127168;      // 32
  float* mur2 = ws + 18127200;      // 32

  hipMemcpyAsync(xbuf, x_in, (size_t)LCHW * 4, hipMemcpyDeviceToDevice,
                 stream);
  hipMemsetAsync(acc1, 0, 64 * 4, stream);  // acc1 + acc2 (adjacent)
  prep_kernel<<<4, 256, 0, stream>>>(Wa, Wk, W2, weff, w2t);
  stats_kernel<<<4096, 256, 0, stream>>>(xbuf, acc1);
  sfinal_kernel<<<1, 64, 0, stream>>>(acc1, mur1, acc2);

  for (int d = 0; d < 4; ++d) {
    vb_kernel<<<dim3(8, 8, 16), 256, 0, stream>>>(
        xbuf, ln1_g + (size_t)d * CHW, ln1_b + (size_t)d * CHW,
        Wv + d * 4096, bv + d * 64, weff + d * 1600, mur1, V, Bbuf);
    attnc_kernel<<<4096, 256, 0, stream>>>(V, Bbuf, attn);
    update_kernel<<<4096, 256, 0, stream>>>(xbuf, attn);
    stats_kernel<<<4096, 256, 0, stream>>>(xbuf, acc2);
    sfinal_kernel<<<1, 64, 0, stream>>>(acc2, mur2, acc1);
    ffn_kernel<<<1024, 256, 0, stream>>>(
        xbuf, ln2_g + (size_t)d * CHW, ln2_b + (size_t)d * CHW,
        W1 + d * 8192, b1 + d * 128, w2t + d * 8192, b2 + d * 64, mur2);
    stats_kernel<<<4096, 256, 0, stream>>>(xbuf, acc1);
    sfinal_kernel<<<1, 64, 0, stream>>>(acc1, mur1, acc2);
  }
}

// Round 2
// 2880.832 us; speedup vs baseline: 2.1710x; 2.1710x over previous
//
#include <hip/hip_runtime.h>

// Encoder: D=4, L=16, C=64, H=W=128.
// Math simplifications (exact up to fp rounding):
//  * softmax_j(A_i + B_j + ba) == softmax_j(B_j): Q/Wq/bq/ba never needed.
//  * attn[i] identical for all i -> compute attnc[c,p] once, broadcast add.
//  * B = conv5(h, Weff), Weff[ci][tap] = sum_co WaK[co][tap]*Wk[co][ci];
//    bk border term is j-independent -> cancels in softmax.
// Round 1: FFN rewritten as fused MFMA kernel (LN2+GEMM1+leaky+GEMM2+residual
// +stats); stats fused into update and initial copy.

#define HW 16384
#define CHW 1048576
#define LCHW 16777216

typedef unsigned short u16;
typedef __attribute__((ext_vector_type(8))) short bf16x8;
typedef __attribute__((ext_vector_type(4))) float f32x4;

static __device__ __forceinline__ u16 f2bf(float f) {
  union { float f; unsigned int u; } v; v.f = f;
  unsigned int r = v.u + 0x7fffu + ((v.u >> 16) & 1u);
  return (u16)(r >> 16);
}
static __device__ __forceinline__ float bf2f(u16 h) {
  union { unsigned int u; float f; } v; v.u = ((unsigned int)h) << 16;
  return v.f;
}

// ---- precompute weff (fp32), W1/W2 bf16 MFMA A-fragment packs ----
__global__ __launch_bounds__(256) void prep_kernel(
    const float* __restrict__ Wa, const float* __restrict__ Wk,
    const float* __restrict__ W1, const float* __restrict__ W2,
    float* __restrict__ weff, u16* __restrict__ w1pk, u16* __restrict__ w2pk) {
  int d = blockIdx.x, t = threadIdx.x;
  const float* WaK = Wa + ((size_t)d * 128 + 64) * 25;
  const float* Wkd = Wk + d * 4096;
  for (int idx = t; idx < 1600; idx += 256) {
    int ci = idx / 25, tap = idx - ci * 25;
    float s = 0.f;
    for (int co = 0; co < 64; ++co)
      s = fmaf(WaK[co * 25 + tap], Wkd[co * 64 + ci], s);
    weff[d * 1600 + idx] = s;
  }
  // W1 pack: A[m=o(128)][k=ci(64)]; frag(mt 0..7, kt 0..1)
  const float* W1d = W1 + d * 8192;  // [o][ci]
  for (int idx = t; idx < 8192; idx += 256) {
    int frag = idx >> 9, lane = (idx >> 3) & 63, j = idx & 7;
    int mt = frag >> 1, kt = frag & 1;
    int o = mt * 16 + (lane & 15);
    int ci = kt * 32 + (lane >> 4) * 8 + j;
    w1pk[d * 8192 + idx] = f2bf(W1d[o * 64 + ci]);
  }
  // W2 pack: A[m=c(64)][k=o(128)]; frag(mt2 0..3, kt2 0..3)
  const float* W2d = W2 + d * 8192;  // [c][o]
  for (int idx = t; idx < 8192; idx += 256) {
    int frag = idx >> 9, lane = (idx >> 3) & 63, j = idx & 7;
    int mt2 = frag >> 2, kt2 = frag & 3;
    int c = mt2 * 16 + (lane & 15);
    int o = kt2 * 32 + (lane >> 4) * 8 + j;
    w2pk[d * 8192 + idx] = f2bf(W2d[c * 128 + o]);
  }
}

// ---- copy x_in -> xbuf and accumulate per-frame stats ----
__global__ __launch_bounds__(256) void copystats_kernel(
    const float* __restrict__ xin, float* __restrict__ xout,
    float* __restrict__ acc) {
  int tid = threadIdx.x;
  size_t base = (size_t)blockIdx.x * 4096;
  const float4* in4 = (const float4*)(xin + base);
  float4* out4 = (float4*)(xout + base);
  float s = 0.f, q = 0.f;
#pragma unroll
  for (int k = 0; k < 4; ++k) {
    float4 v = in4[k * 256 + tid];
    out4[k * 256 + tid] = v;
    s += v.x + v.y + v.z + v.w;
    q = fmaf(v.x, v.x, q); q = fmaf(v.y, v.y, q);
    q = fmaf(v.z, v.z, q); q = fmaf(v.w, v.w, q);
  }
#pragma unroll
  for (int off = 32; off > 0; off >>= 1) {
    s += __shfl_down(s, off); q += __shfl_down(q, off);
  }
  __shared__ float ls[4], lq[4];
  int wave = tid >> 6;
  if ((tid & 63) == 0) { ls[wave] = s; lq[wave] = q; }
  __syncthreads();
  if (tid == 0) {
    int frame = blockIdx.x >> 8;
    atomicAdd(&acc[frame * 2], ls[0] + ls[1] + ls[2] + ls[3]);
    atomicAdd(&acc[frame * 2 + 1], lq[0] + lq[1] + lq[2] + lq[3]);
  }
}

// ---- finalize mu / rsqrt(var+eps); zero the other accumulator ----
__global__ __launch_bounds__(64) void sfinal_kernel(
    const float* __restrict__ acc, float* __restrict__ mur,
    float* __restrict__ accz) {
  int t = threadIdx.x;
  if (t < 16) {
    const float invN = 1.f / 1048576.f;
    float s = acc[2 * t], q = acc[2 * t + 1];
    float mu = s * invN;
    float var = q * invN - mu * mu;
    mur[2 * t] = mu;
    mur[2 * t + 1] = rsqrtf(var + 1e-5f);
  }
  if (t < 32) accz[t] = 0.f;
}

// ---- fused LN1 + V (1x1 conv) + B (5x5 conv with Weff) ----
__global__ __launch_bounds__(256) void vb_kernel(
    const float* __restrict__ x, const float* __restrict__ g,
    const float* __restrict__ bln, const float* __restrict__ Wv,
    const float* __restrict__ bv, const float* __restrict__ weff,
    const float* __restrict__ mur, float* __restrict__ V,
    float* __restrict__ Bout) {
  __shared__ u16 sh[64][400];
  int l = blockIdx.z;
  int ty0 = blockIdx.y * 16, tx0 = blockIdx.x * 16;
  int tid = threadIdx.x;
  float mu = mur[2 * l], r = mur[2 * l + 1];
  for (int idx = tid; idx < 64 * 400; idx += 256) {
    int ci = idx / 400, q = idx - ci * 400;
    int row = q / 20, col = q - row * 20;
    int yy = ty0 + row - 2, xx = tx0 + col - 2;
    float v = 0.f;
    if (yy >= 0 && yy < 128 && xx >= 0 && xx < 128) {
      int pix = (yy << 7) + xx;
      size_t gi = (((size_t)l * 64 + ci) << 14) + pix;
      int li = (ci << 14) + pix;
      v = (x[gi] - mu) * r * g[li] + bln[li];
    }
    sh[ci][q] = f2bf(v);
  }
  __syncthreads();
  int ty = tid >> 4, tx = tid & 15;
  int pc = (ty + 2) * 20 + (tx + 2);
  float h[64];
#pragma unroll
  for (int ci = 0; ci < 64; ++ci) h[ci] = bf2f(sh[ci][pc]);
  int gy = ty0 + ty, gx = tx0 + tx;
  size_t opix = ((size_t)gy << 7) + gx;
  for (int co = 0; co < 64; ++co) {
    const float* wr = Wv + (co << 6);
    float a0 = 0.f, a1 = 0.f, a2 = 0.f, a3 = 0.f;
#pragma unroll
    for (int ci = 0; ci < 64; ci += 4) {
      a0 = fmaf(wr[ci], h[ci], a0);
      a1 = fmaf(wr[ci + 1], h[ci + 1], a1);
      a2 = fmaf(wr[ci + 2], h[ci + 2], a2);
      a3 = fmaf(wr[ci + 3], h[ci + 3], a3);
    }
    V[(((size_t)l * 64 + co) << 14) + opix] = (a0 + a1) + (a2 + a3) + bv[co];
  }
  float b0 = 0.f, b1_ = 0.f, b2_ = 0.f, b3 = 0.f;
  for (int ci = 0; ci < 64; ++ci) {
    const float* wrow = weff + ci * 25;
#pragma unroll
    for (int dy = 0; dy < 5; ++dy) {
      int rb = (ty + dy) * 20 + tx;
#pragma unroll
      for (int dx = 0; dx < 5; ++dx) {
        float hv = bf2f(sh[ci][rb + dx]);
        int k = dy * 5 + dx;
        float w = wrow[k];
        if ((k & 3) == 0) b0 = fmaf(w, hv, b0);
        else if ((k & 3) == 1) b1_ = fmaf(w, hv, b1_);
        else if ((k & 3) == 2) b2_ = fmaf(w, hv, b2_);
        else b3 = fmaf(w, hv, b3);
      }
    }
  }
  Bout[((size_t)l << 14) + opix] = (b0 + b1_) + (b2_ + b3);
}

// ---- attnc[c,p] = sum_j softmax_j(B[j,p]) * V[j,c,p] ----
__global__ __launch_bounds__(256) void attnc_kernel(
    const float* __restrict__ V, const float* __restrict__ B,
    float* __restrict__ attnc) {
  int gid = blockIdx.x * 256 + threadIdx.x;
  int p = gid & 16383, c = gid >> 14;
  float bj[16];
  float m = -1e30f;
#pragma unroll
  for (int j = 0; j < 16; ++j) {
    bj[j] = B[(j << 14) + p];
    m = fmaxf(m, bj[j]);
  }
  float sum = 0.f;
#pragma unroll
  for (int j = 0; j < 16; ++j) {
    bj[j] = __expf(bj[j] - m);
    sum += bj[j];
  }
  float inv = 1.f / sum;
  float a = 0.f;
#pragma unroll
  for (int j = 0; j < 16; ++j)
    a = fmaf(bj[j], V[(((size_t)j * 64 + c) << 14) + p], a);
  attnc[gid] = a * inv;
}

// ---- x[f] += attnc (broadcast) and accumulate per-frame stats ----
__global__ __launch_bounds__(256) void update_stats_kernel(
    float* __restrict__ x, const float* __restrict__ attnc,
    float* __restrict__ acc) {
  int tid = threadIdx.x;
  int f = blockIdx.x >> 8, chunk = blockIdx.x & 255;
  const float4* a4 = (const float4*)attnc;
  float4* x4 = (float4*)x;
  float s = 0.f, q = 0.f;
#pragma unroll
  for (int k = 0; k < 4; ++k) {
    int idx4 = chunk * 1024 + k * 256 + tid;
    float4 a = a4[idx4];
    size_t xi = ((size_t)f << 18) + idx4;
    float4 v = x4[xi];
    v.x += a.x; v.y += a.y; v.z += a.z; v.w += a.w;
    x4[xi] = v;
    s += v.x + v.y + v.z + v.w;
    q = fmaf(v.x, v.x, q); q = fmaf(v.y, v.y, q);
    q = fmaf(v.z, v.z, q); q = fmaf(v.w, v.w, q);
  }
#pragma unroll
  for (int off = 32; off > 0; off >>= 1) {
    s += __shfl_down(s, off); q += __shfl_down(q, off);
  }
  __shared__ float ls[4], lq[4];
  int wave = tid >> 6;
  if ((tid & 63) == 0) { ls[wave] = s; lq[wave] = q; }
  __syncthreads();
  if (tid == 0) {
    atomicAdd(&acc[f * 2], ls[0] + ls[1] + ls[2] + ls[3]);
    atomicAdd(&acc[f * 2 + 1], lq[0] + lq[1] + lq[2] + lq[3]);
  }
}

// ---- fused LN2 + FFN via MFMA + residual + stats for next LN1 ----
// Block: 128 pixels of one frame. LDS: h[128][72]bf16 | W1pack 16KB, then
// f1[128][136]bf16 overlays both; W2pack 16KB separate. 50KB total.
__global__ __launch_bounds__(256) void ffn_kernel(
    float* __restrict__ x, const float* __restrict__ g,
    const float* __restrict__ bln, const u16* __restrict__ w1p_g,
    const float* __restrict__ b1, const u16* __restrict__ w2p_g,
    const float* __restrict__ b2, const float* __restrict__ mur,
    float* __restrict__ acc) {
  __shared__ __align__(16) char lds[51200];
  u16* hbase = (u16*)lds;                 // rows stride 72
  u16* w1l = (u16*)(lds + 18432);
  u16* f1base = (u16*)lds;                // rows stride 136 (overlays h+w1l)
  u16* w2l = (u16*)(lds + 34816);

  int tid = threadIdx.x;
  int P0 = blockIdx.x << 7;
  int l = P0 >> 14;
  int p0 = P0 & 16383;
  float mu = mur[2 * l], r = mur[2 * l + 1];

  // stage weight packs
  const uint4* w1g4 = (const uint4*)w1p_g;
  const uint4* w2g4 = (const uint4*)w2p_g;
  uint4* w1l4 = (uint4*)w1l;
  uint4* w2l4 = (uint4*)w2l;
  for (int i = tid; i < 1024; i += 256) w1l4[i] = w1g4[i];
  for (int i = tid; i < 1024; i += 256) w2l4[i] = w2g4[i];

  // stage x -> h (LN2 applied, bf16), layout h[px][ci]
#pragma unroll
  for (int it = 0; it < 8; ++it) {
    int e = it * 1024 + tid * 4;
    int c = e >> 7, px = e & 127;
    size_t gi = (((size_t)l * 64 + c) << 14) + p0 + px;
    int li = (c << 14) + p0 + px;
    float4 xv = *(const float4*)(x + gi);
    float4 gv = *(const float4*)(g + li);
    float4 bv = *(const float4*)(bln + li);
    hbase[(px + 0) * 72 + c] = f2bf((xv.x - mu) * r * gv.x + bv.x);
    hbase[(px + 1) * 72 + c] = f2bf((xv.y - mu) * r * gv.y + bv.y);
    hbase[(px + 2) * 72 + c] = f2bf((xv.z - mu) * r * gv.z + bv.z);
    hbase[(px + 3) * 72 + c] = f2bf((xv.w - mu) * r * gv.w + bv.w);
  }
  __syncthreads();

  int wv = tid >> 6, lane = tid & 63;
  int ln15 = lane & 15, quad = lane >> 4;

  // GEMM1: D[o=128][pix] = W1 x h ; wave handles n-tiles {2wv, 2wv+1}
  bf16x8 a1[8][2];
#pragma unroll
  for (int mt = 0; mt < 8; ++mt)
#pragma unroll
    for (int kt = 0; kt < 2; ++kt)
      a1[mt][kt] = *(const bf16x8*)(w1l + ((mt * 2 + kt) * 64 + lane) * 8);
  bf16x8 bh[2][2];
#pragma unroll
  for (int nt2 = 0; nt2 < 2; ++nt2) {
    int px = (wv * 2 + nt2) * 16 + ln15;
#pragma unroll
    for (int kt = 0; kt < 2; ++kt)
      bh[nt2][kt] = *(const bf16x8*)(hbase + px * 72 + kt * 32 + quad * 8);
  }
  f32x4 acc1[2][8];
#pragma unroll
  for (int nt2 = 0; nt2 < 2; ++nt2)
#pragma unroll
    for (int mt = 0; mt < 8; ++mt)
      acc1[nt2][mt] = (f32x4){0.f, 0.f, 0.f, 0.f};
#pragma unroll
  for (int mt = 0; mt < 8; ++mt)
#pragma unroll
    for (int kt = 0; kt < 2; ++kt)
#pragma unroll
      for (int nt2 = 0; nt2 < 2; ++nt2)
        acc1[nt2][mt] = __builtin_amdgcn_mfma_f32_16x16x32_bf16(
            a1[mt][kt], bh[nt2][kt], acc1[nt2][mt], 0, 0, 0);
  __syncthreads();  // everyone done reading h/w1l

  // bias + leaky + write f1[px][o] bf16
#pragma unroll
  for (int nt2 = 0; nt2 < 2; ++nt2) {
    int px = (wv * 2 + nt2) * 16 + ln15;
#pragma unroll
    for (int mt = 0; mt < 8; ++mt) {
      f32x4 v = acc1[nt2][mt];
#pragma unroll
      for (int rj = 0; rj < 4; ++rj) {
        int o = mt * 16 + quad * 4 + rj;
        float f = v[rj] + b1[o];
        f = fmaxf(f, 0.01f * f);
        f1base[px * 136 + o] = f2bf(f);
      }
    }
  }
  __syncthreads();

  // GEMM2: D[c=64][pix] = W2 x f1
  bf16x8 a2[4][4];
#pragma unroll
  for (int mt2 = 0; mt2 < 4; ++mt2)
#pragma unroll
    for (int kt2 = 0; kt2 < 4; ++kt2)
      a2[mt2][kt2] = *(const bf16x8*)(w2l + ((mt2 * 4 + kt2) * 64 + lane) * 8);
  bf16x8 bf2[2][4];
#pragma unroll
  for (int nt2 = 0; nt2 < 2; ++nt2) {
    int px = (wv * 2 + nt2) * 16 + ln15;
#pragma unroll
    for (int kt2 = 0; kt2 < 4; ++kt2)
      bf2[nt2][kt2] =
          *(const bf16x8*)(f1base + px * 136 + kt2 * 32 + quad * 8);
  }
  f32x4 acc2[2][4];
#pragma unroll
  for (int nt2 = 0; nt2 < 2; ++nt2)
#pragma unroll
    for (int mt2 = 0; mt2 < 4; ++mt2)
      acc2[nt2][mt2] = (f32x4){0.f, 0.f, 0.f, 0.f};
#pragma unroll
  for (int mt2 = 0; mt2 < 4; ++mt2)
#pragma unroll
    for (int kt2 = 0; kt2 < 4; ++kt2)
#pragma unroll
      for (int nt2 = 0; nt2 < 2; ++nt2)
        acc2[nt2][mt2] = __builtin_amdgcn_mfma_f32_16x16x32_bf16(
            a2[mt2][kt2], bf2[nt2][kt2], acc2[nt2][mt2], 0, 0, 0);

  // epilogue: residual add, store, stats
  float s = 0.f, q = 0.f;
#pragma unroll
  for (int nt2 = 0; nt2 < 2; ++nt2) {
    int gp = p0 + (wv * 2 + nt2) * 16 + ln15;
#pragma unroll
    for (int mt2 = 0; mt2 < 4; ++mt2) {
#pragma unroll
      for (int rj = 0; rj < 4; ++rj) {
        int c = mt2 * 16 + quad * 4 + rj;
        size_t gi = (((size_t)l * 64 + c) << 14) + gp;
        float xn = x[gi] + acc2[nt2][mt2][rj] + b2[c];
        x[gi] = xn;
        s += xn;
        q = fmaf(xn, xn, q);
      }
    }
  }
#pragma unroll
  for (int off = 32; off > 0; off >>= 1) {
    s += __shfl_down(s, off); q += __shfl_down(q, off);
  }
  if (lane == 0) {
    atomicAdd(&acc[l * 2], s);
    atomicAdd(&acc[l * 2 + 1], q);
  }
}

extern "C" void kernel_launch(void* const* d_in, const int* in_sizes, int n_in,
                              void* d_out, int out_size, void* d_ws,
                              size_t ws_size, hipStream_t stream) {
  const float* x_in = (const float*)d_in[0];
  const float* ln1_g = (const float*)d_in[1];
  const float* ln1_b = (const float*)d_in[2];
  const float* Wk = (const float*)d_in[5];
  const float* Wv = (const float*)d_in[7];
  const float* bv = (const float*)d_in[8];
  const float* Wa = (const float*)d_in[9];
  const float* ln2_g = (const float*)d_in[11];
  const float* ln2_b = (const float*)d_in[12];
  const float* W1 = (const float*)d_in[13];
  const float* b1 = (const float*)d_in[14];
  const float* W2 = (const float*)d_in[15];
  const float* b2 = (const float*)d_in[16];

  float* xbuf = (float*)d_out;
  float* ws = (float*)d_ws;
  float* V = ws;                     // 16777216
  float* attn = ws + 16777216;       // 1048576
  float* Bbuf = ws + 17825792;       // 262144
  float* weff = ws + 18087936;       // 6400
  u16* w1pk = (u16*)(ws + 18094336); // 32768 u16 (16384 float slots)
  u16* w2pk = (u16*)(ws + 18110720); // 32768 u16
  float* accA = ws + 18127104;       // 32
  float* accB = ws + 18127136;       // 32
  float* mur1 = ws + 18127168;       // 32
  float* mur2 = ws + 18127200;       // 32

  hipMemsetAsync(accA, 0, 256, stream);  // accA + accB
  prep_kernel<<<4, 256, 0, stream>>>(Wa, Wk, W1, W2, weff, w1pk, w2pk);
  copystats_kernel<<<4096, 256, 0, stream>>>(x_in, xbuf, accA);
  sfinal_kernel<<<1, 64, 0, stream>>>(accA, mur1, accB);

  for (int d = 0; d < 4; ++d) {
    vb_kernel<<<dim3(8, 8, 16), 256, 0, stream>>>(
        xbuf, ln1_g + (size_t)d * CHW, ln1_b + (size_t)d * CHW,
        Wv + d * 4096, bv + d * 64, weff + d * 1600, mur1, V, Bbuf);
    attnc_kernel<<<4096, 256, 0, stream>>>(V, Bbuf, attn);
    update_stats_kernel<<<4096, 256, 0, stream>>>(xbuf, attn, accB);
    sfinal_kernel<<<1, 64, 0, stream>>>(accB, mur2, accA);
    ffn_kernel<<<2048, 256, 0, stream>>>(
        xbuf, ln2_g + (size_t)d * CHW, ln2_b + (size_t)d * CHW,
        w1pk + d * 8192, b1 + d * 128, w2pk + d * 8192, b2 + d * 64, mur2,
        accA);
    sfinal_kernel<<<1, 64, 0, stream>>>(accA, mur1, accB);
  }
}

// Round 3
// 1723.563 us; speedup vs baseline: 3.6288x; 1.6714x over previous
//
#include <hip/hip_runtime.h>

// Encoder: D=4, L=16, C=64, H=W=128.
// Math simplifications (exact up to fp rounding):
//  * softmax_j(A_i + B_j + ba) == softmax_j(B_j): Q/Wq/bq/ba never needed.
//  * attn[i] identical for all i -> compute attnc[c,p] once, broadcast add.
//  * B = conv5(h, Weff), Weff[tap][ci] = sum_co WaK[co][tap]*Wk[co][ci];
//    bk border term is j-independent -> cancels in softmax.
//  * conv5 via GEMM: T[tap][p] = sum_ci Weff[tap][ci]*h[ci][p] (MFMA, taps
//    padded to 32), then B[p] = sum_tap T[tap][p+off(tap)] (shift-add).
// Round 2: vb rewritten as MFMA (V GEMM + T GEMM sharing h fragments);
// V stored bf16; new bconv shift-add kernel.

#define HW 16384
#define CHW 1048576
#define LCHW 16777216

typedef unsigned short u16;
typedef __attribute__((ext_vector_type(8))) short bf16x8;
typedef __attribute__((ext_vector_type(4))) float f32x4;

static __device__ __forceinline__ u16 f2bf(float f) {
  union { float f; unsigned int u; } v; v.f = f;
  unsigned int r = v.u + 0x7fffu + ((v.u >> 16) & 1u);
  return (u16)(r >> 16);
}
static __device__ __forceinline__ float bf2f(u16 h) {
  union { unsigned int u; float f; } v; v.u = ((unsigned int)h) << 16;
  return v.f;
}

// ---- precompute bf16 MFMA A-fragment packs: W1, W2, Wv, Weff ----
// A-frag convention (16x16x32): m = mt*16 + (lane&15), k = kt*32 +
// (lane>>4)*8 + j; element at pack[((mt*KT+kt)*64 + lane)*8 + j].
__global__ __launch_bounds__(256) void prep_kernel(
    const float* __restrict__ Wa, const float* __restrict__ Wk,
    const float* __restrict__ Wv, const float* __restrict__ W1,
    const float* __restrict__ W2, u16* __restrict__ w1pk,
    u16* __restrict__ w2pk, u16* __restrict__ wvpk, u16* __restrict__ wepk) {
  int d = blockIdx.x, t = threadIdx.x;
  const float* WaK = Wa + ((size_t)d * 128 + 64) * 25;
  const float* Wkd = Wk + d * 4096;
  // Weff pack: m=tap (25 padded to 32, 2 mt), k=ci (2 kt) -> 4 frags
  for (int idx = t; idx < 2048; idx += 256) {
    int frag = idx >> 9, lane = (idx >> 3) & 63, j = idx & 7;
    int mt = frag >> 1, kt = frag & 1;
    int tap = mt * 16 + (lane & 15);
    int ci = kt * 32 + (lane >> 4) * 8 + j;
    float s = 0.f;
    if (tap < 25)
      for (int co = 0; co < 64; ++co)
        s = fmaf(WaK[co * 25 + tap], Wkd[co * 64 + ci], s);
    wepk[d * 2048 + idx] = f2bf(s);
  }
  // Wv pack: m=co (4 mt), k=ci (2 kt) -> 8 frags
  const float* Wvd = Wv + d * 4096;
  for (int idx = t; idx < 4096; idx += 256) {
    int frag = idx >> 9, lane = (idx >> 3) & 63, j = idx & 7;
    int mt = frag >> 1, kt = frag & 1;
    int co = mt * 16 + (lane & 15);
    int ci = kt * 32 + (lane >> 4) * 8 + j;
    wvpk[d * 4096 + idx] = f2bf(Wvd[co * 64 + ci]);
  }
  // W1 pack: m=o(128, 8 mt), k=ci(64, 2 kt)
  const float* W1d = W1 + d * 8192;
  for (int idx = t; idx < 8192; idx += 256) {
    int frag = idx >> 9, lane = (idx >> 3) & 63, j = idx & 7;
    int mt = frag >> 1, kt = frag & 1;
    int o = mt * 16 + (lane & 15);
    int ci = kt * 32 + (lane >> 4) * 8 + j;
    w1pk[d * 8192 + idx] = f2bf(W1d[o * 64 + ci]);
  }
  // W2 pack: m=c(64, 4 mt2), k=o(128, 4 kt2)
  const float* W2d = W2 + d * 8192;
  for (int idx = t; idx < 8192; idx += 256) {
    int frag = idx >> 9, lane = (idx >> 3) & 63, j = idx & 7;
    int mt2 = frag >> 2, kt2 = frag & 3;
    int c = mt2 * 16 + (lane & 15);
    int o = kt2 * 32 + (lane >> 4) * 8 + j;
    w2pk[d * 8192 + idx] = f2bf(W2d[c * 128 + o]);
  }
}

// ---- copy x_in -> xbuf and accumulate per-frame stats ----
__global__ __launch_bounds__(256) void copystats_kernel(
    const float* __restrict__ xin, float* __restrict__ xout,
    float* __restrict__ acc) {
  int tid = threadIdx.x;
  size_t base = (size_t)blockIdx.x * 4096;
  const float4* in4 = (const float4*)(xin + base);
  float4* out4 = (float4*)(xout + base);
  float s = 0.f, q = 0.f;
#pragma unroll
  for (int k = 0; k < 4; ++k) {
    float4 v = in4[k * 256 + tid];
    out4[k * 256 + tid] = v;
    s += v.x + v.y + v.z + v.w;
    q = fmaf(v.x, v.x, q); q = fmaf(v.y, v.y, q);
    q = fmaf(v.z, v.z, q); q = fmaf(v.w, v.w, q);
  }
#pragma unroll
  for (int off = 32; off > 0; off >>= 1) {
    s += __shfl_down(s, off); q += __shfl_down(q, off);
  }
  __shared__ float ls[4], lq[4];
  int wave = tid >> 6;
  if ((tid & 63) == 0) { ls[wave] = s; lq[wave] = q; }
  __syncthreads();
  if (tid == 0) {
    int frame = blockIdx.x >> 8;
    atomicAdd(&acc[frame * 2], ls[0] + ls[1] + ls[2] + ls[3]);
    atomicAdd(&acc[frame * 2 + 1], lq[0] + lq[1] + lq[2] + lq[3]);
  }
}

// ---- finalize mu / rsqrt(var+eps); zero the other accumulator ----
__global__ __launch_bounds__(64) void sfinal_kernel(
    const float* __restrict__ acc, float* __restrict__ mur,
    float* __restrict__ accz) {
  int t = threadIdx.x;
  if (t < 16) {
    const float invN = 1.f / 1048576.f;
    float s = acc[2 * t], q = acc[2 * t + 1];
    float mu = s * invN;
    float var = q * invN - mu * mu;
    mur[2 * t] = mu;
    mur[2 * t + 1] = rsqrtf(var + 1e-5f);
  }
  if (t < 32) accz[t] = 0.f;
}

// ---- fused LN1 + V GEMM (bf16 out) + T GEMM (conv tap planes) ----
// Block: 128 pixels of one frame. LDS: h[128 rows][72] bf16 (XOR-swizzled
// cols), Wv pack 8KB, Weff pack 4KB -> 30720 B.
__global__ __launch_bounds__(256) void vb_kernel(
    const float* __restrict__ x, const float* __restrict__ g,
    const float* __restrict__ bln, const u16* __restrict__ wvp_g,
    const float* __restrict__ bv, const u16* __restrict__ wep_g,
    const float* __restrict__ mur, u16* __restrict__ Vb,
    float* __restrict__ T) {
  __shared__ __align__(16) char lds[30720];
  u16* hb = (u16*)lds;                    // rows stride 72 u16
  u16* wvl = (u16*)(lds + 18432);
  u16* wel = (u16*)(lds + 26624);
  int tid = threadIdx.x;
  int l = blockIdx.y;
  int p0 = blockIdx.x << 7;
  float mu = mur[2 * l], r = mur[2 * l + 1];

  // stage weight packs
  const uint4* wv4 = (const uint4*)wvp_g;
  const uint4* we4 = (const uint4*)wep_g;
  uint4* wvl4 = (uint4*)wvl;
  uint4* wel4 = (uint4*)wel;
  wvl4[tid] = wv4[tid];
  wvl4[tid + 256] = wv4[tid + 256];
  wel4[tid] = we4[tid];

  // stage h[px][ci] (LN1 applied, bf16). Thread handles 2 iterations of
  // a (4 ci) x (4 px) block; writes are ds_write_b64 with XOR swizzle.
#pragma unroll
  for (int it = 0; it < 2; ++it) {
    int pq = tid & 31, cg = (tid >> 5) + it * 8;
    int px = pq * 4, c0 = cg * 4;
    float vv[4][4];
#pragma unroll
    for (int i = 0; i < 4; ++i) {
      int c = c0 + i;
      size_t gi = (((size_t)l * 64 + c) << 14) + p0 + px;
      int li = (c << 14) + p0 + px;
      float4 xv = *(const float4*)(x + gi);
      float4 gv = *(const float4*)(g + li);
      float4 bb = *(const float4*)(bln + li);
      vv[i][0] = (xv.x - mu) * r * gv.x + bb.x;
      vv[i][1] = (xv.y - mu) * r * gv.y + bb.y;
      vv[i][2] = (xv.z - mu) * r * gv.z + bb.z;
      vv[i][3] = (xv.w - mu) * r * gv.w + bb.w;
    }
#pragma unroll
    for (int k = 0; k < 4; ++k) {
      int row = px + k;
      int col = c0 ^ ((row & 7) * 8);
      ushort4 hv;
      hv.x = f2bf(vv[0][k]); hv.y = f2bf(vv[1][k]);
      hv.z = f2bf(vv[2][k]); hv.w = f2bf(vv[3][k]);
      *(ushort4*)(hb + row * 72 + col) = hv;
    }
  }
  __syncthreads();

  int wv = tid >> 6, lane = tid & 63;
  int ln15 = lane & 15, quad = lane >> 4;

  // A fragments
  bf16x8 av[4][2], ae[2][2];
#pragma unroll
  for (int mt = 0; mt < 4; ++mt)
#pragma unroll
    for (int kt = 0; kt < 2; ++kt)
      av[mt][kt] = *(const bf16x8*)(wvl + ((mt * 2 + kt) * 64 + lane) * 8);
#pragma unroll
  for (int mt = 0; mt < 2; ++mt)
#pragma unroll
    for (int kt = 0; kt < 2; ++kt)
      ae[mt][kt] = *(const bf16x8*)(wel + ((mt * 2 + kt) * 64 + lane) * 8);

  // B fragments: wave handles n-tiles {2wv, 2wv+1}
  bf16x8 bh[2][2];
#pragma unroll
  for (int nt = 0; nt < 2; ++nt) {
    int px = (wv * 2 + nt) * 16 + ln15;
    int swz = (px & 7) * 8;
#pragma unroll
    for (int kt = 0; kt < 2; ++kt) {
      int col = (kt * 32 + quad * 8) ^ swz;
      bh[nt][kt] = *(const bf16x8*)(hb + px * 72 + col);
    }
  }

  f32x4 accV[2][4], accT[2][2];
#pragma unroll
  for (int nt = 0; nt < 2; ++nt) {
#pragma unroll
    for (int mt = 0; mt < 4; ++mt) accV[nt][mt] = (f32x4){0.f, 0.f, 0.f, 0.f};
#pragma unroll
    for (int mt = 0; mt < 2; ++mt) accT[nt][mt] = (f32x4){0.f, 0.f, 0.f, 0.f};
  }
#pragma unroll
  for (int mt = 0; mt < 4; ++mt)
#pragma unroll
    for (int kt = 0; kt < 2; ++kt)
#pragma unroll
      for (int nt = 0; nt < 2; ++nt)
        accV[nt][mt] = __builtin_amdgcn_mfma_f32_16x16x32_bf16(
            av[mt][kt], bh[nt][kt], accV[nt][mt], 0, 0, 0);
#pragma unroll
  for (int mt = 0; mt < 2; ++mt)
#pragma unroll
    for (int kt = 0; kt < 2; ++kt)
#pragma unroll
      for (int nt = 0; nt < 2; ++nt)
        accT[nt][mt] = __builtin_amdgcn_mfma_f32_16x16x32_bf16(
            ae[mt][kt], bh[nt][kt], accT[nt][mt], 0, 0, 0);

  // epilogue: V (bf16, +bias), T (fp32, taps < 25)
#pragma unroll
  for (int nt = 0; nt < 2; ++nt) {
    int gp = p0 + (wv * 2 + nt) * 16 + ln15;
#pragma unroll
    for (int mt = 0; mt < 4; ++mt) {
#pragma unroll
      for (int rj = 0; rj < 4; ++rj) {
        int co = mt * 16 + quad * 4 + rj;
        Vb[(((size_t)l * 64 + co) << 14) + gp] =
            f2bf(accV[nt][mt][rj] + bv[co]);
      }
    }
#pragma unroll
    for (int mt = 0; mt < 2; ++mt) {
#pragma unroll
      for (int rj = 0; rj < 4; ++rj) {
        int tap = mt * 16 + quad * 4 + rj;
        if (tap < 25)
          T[(((size_t)l * 25 + tap) << 14) + gp] = accT[nt][mt][rj];
      }
    }
  }
}

// ---- B[l][p] = sum_tap T[l][tap][p + off(tap)] (zero-padded) ----
__global__ __launch_bounds__(256) void bconv_kernel(
    const float* __restrict__ T, float* __restrict__ B) {
  int gid = blockIdx.x * 256 + threadIdx.x;  // l*HW + p
  int l = gid >> 14, p = gid & 16383;
  int y = p >> 7, xx = p & 127;
  float s = 0.f;
#pragma unroll
  for (int dy = 0; dy < 5; ++dy) {
    int yy = y + dy - 2;
    if (yy < 0 || yy > 127) continue;
#pragma unroll
    for (int dx = 0; dx < 5; ++dx) {
      int xc = xx + dx - 2;
      if (xc < 0 || xc > 127) continue;
      s += T[(((size_t)l * 25 + dy * 5 + dx) << 14) + (yy << 7) + xc];
    }
  }
  B[gid] = s;
}

// ---- attnc[c,p] = sum_j softmax_j(B[j,p]) * V[j,c,p] ----
__global__ __launch_bounds__(256) void attnc_kernel(
    const u16* __restrict__ V, const float* __restrict__ B,
    float* __restrict__ attnc) {
  int gid = blockIdx.x * 256 + threadIdx.x;
  int p = gid & 16383, c = gid >> 14;
  float bj[16];
  float m = -1e30f;
#pragma unroll
  for (int j = 0; j < 16; ++j) {
    bj[j] = B[(j << 14) + p];
    m = fmaxf(m, bj[j]);
  }
  float sum = 0.f;
#pragma unroll
  for (int j = 0; j < 16; ++j) {
    bj[j] = __expf(bj[j] - m);
    sum += bj[j];
  }
  float inv = 1.f / sum;
  float a = 0.f;
#pragma unroll
  for (int j = 0; j < 16; ++j)
    a = fmaf(bj[j], bf2f(V[(((size_t)j * 64 + c) << 14) + p]), a);
  attnc[gid] = a * inv;
}

// ---- x[f] += attnc (broadcast) and accumulate per-frame stats ----
__global__ __launch_bounds__(256) void update_stats_kernel(
    float* __restrict__ x, const float* __restrict__ attnc,
    float* __restrict__ acc) {
  int tid = threadIdx.x;
  int f = blockIdx.x >> 8, chunk = blockIdx.x & 255;
  const float4* a4 = (const float4*)attnc;
  float4* x4 = (float4*)x;
  float s = 0.f, q = 0.f;
#pragma unroll
  for (int k = 0; k < 4; ++k) {
    int idx4 = chunk * 1024 + k * 256 + tid;
    float4 a = a4[idx4];
    size_t xi = ((size_t)f << 18) + idx4;
    float4 v = x4[xi];
    v.x += a.x; v.y += a.y; v.z += a.z; v.w += a.w;
    x4[xi] = v;
    s += v.x + v.y + v.z + v.w;
    q = fmaf(v.x, v.x, q); q = fmaf(v.y, v.y, q);
    q = fmaf(v.z, v.z, q); q = fmaf(v.w, v.w, q);
  }
#pragma unroll
  for (int off = 32; off > 0; off >>= 1) {
    s += __shfl_down(s, off); q += __shfl_down(q, off);
  }
  __shared__ float ls[4], lq[4];
  int wave = tid >> 6;
  if ((tid & 63) == 0) { ls[wave] = s; lq[wave] = q; }
  __syncthreads();
  if (tid == 0) {
    atomicAdd(&acc[f * 2], ls[0] + ls[1] + ls[2] + ls[3]);
    atomicAdd(&acc[f * 2 + 1], lq[0] + lq[1] + lq[2] + lq[3]);
  }
}

// ---- fused LN2 + FFN via MFMA + residual + stats for next LN1 ----
__global__ __launch_bounds__(256) void ffn_kernel(
    float* __restrict__ x, const float* __restrict__ g,
    const float* __restrict__ bln, const u16* __restrict__ w1p_g,
    const float* __restrict__ b1, const u16* __restrict__ w2p_g,
    const float* __restrict__ b2, const float* __restrict__ mur,
    float* __restrict__ acc) {
  __shared__ __align__(16) char lds[51200];
  u16* hbase = (u16*)lds;                 // rows stride 72
  u16* w1l = (u16*)(lds + 18432);
  u16* f1base = (u16*)lds;                // rows stride 136 (overlays h+w1l)
  u16* w2l = (u16*)(lds + 34816);

  int tid = threadIdx.x;
  int P0 = blockIdx.x << 7;
  int l = P0 >> 14;
  int p0 = P0 & 16383;
  float mu = mur[2 * l], r = mur[2 * l + 1];

  const uint4* w1g4 = (const uint4*)w1p_g;
  const uint4* w2g4 = (const uint4*)w2p_g;
  uint4* w1l4 = (uint4*)w1l;
  uint4* w2l4 = (uint4*)w2l;
  for (int i = tid; i < 1024; i += 256) w1l4[i] = w1g4[i];
  for (int i = tid; i < 1024; i += 256) w2l4[i] = w2g4[i];

#pragma unroll
  for (int it = 0; it < 8; ++it) {
    int e = it * 1024 + tid * 4;
    int c = e >> 7, px = e & 127;
    size_t gi = (((size_t)l * 64 + c) << 14) + p0 + px;
    int li = (c << 14) + p0 + px;
    float4 xv = *(const float4*)(x + gi);
    float4 gv = *(const float4*)(g + li);
    float4 bv = *(const float4*)(bln + li);
    hbase[(px + 0) * 72 + c] = f2bf((xv.x - mu) * r * gv.x + bv.x);
    hbase[(px + 1) * 72 + c] = f2bf((xv.y - mu) * r * gv.y + bv.y);
    hbase[(px + 2) * 72 + c] = f2bf((xv.z - mu) * r * gv.z + bv.z);
    hbase[(px + 3) * 72 + c] = f2bf((xv.w - mu) * r * gv.w + bv.w);
  }
  __syncthreads();

  int wv = tid >> 6, lane = tid & 63;
  int ln15 = lane & 15, quad = lane >> 4;

  bf16x8 a1[8][2];
#pragma unroll
  for (int mt = 0; mt < 8; ++mt)
#pragma unroll
    for (int kt = 0; kt < 2; ++kt)
      a1[mt][kt] = *(const bf16x8*)(w1l + ((mt * 2 + kt) * 64 + lane) * 8);
  bf16x8 bh[2][2];
#pragma unroll
  for (int nt2 = 0; nt2 < 2; ++nt2) {
    int px = (wv * 2 + nt2) * 16 + ln15;
#pragma unroll
    for (int kt = 0; kt < 2; ++kt)
      bh[nt2][kt] = *(const bf16x8*)(hbase + px * 72 + kt * 32 + quad * 8);
  }
  f32x4 acc1[2][8];
#pragma unroll
  for (int nt2 = 0; nt2 < 2; ++nt2)
#pragma unroll
    for (int mt = 0; mt < 8; ++mt)
      acc1[nt2][mt] = (f32x4){0.f, 0.f, 0.f, 0.f};
#pragma unroll
  for (int mt = 0; mt < 8; ++mt)
#pragma unroll
    for (int kt = 0; kt < 2; ++kt)
#pragma unroll
      for (int nt2 = 0; nt2 < 2; ++nt2)
        acc1[nt2][mt] = __builtin_amdgcn_mfma_f32_16x16x32_bf16(
            a1[mt][kt], bh[nt2][kt], acc1[nt2][mt], 0, 0, 0);
  __syncthreads();

#pragma unroll
  for (int nt2 = 0; nt2 < 2; ++nt2) {
    int px = (wv * 2 + nt2) * 16 + ln15;
#pragma unroll
    for (int mt = 0; mt < 8; ++mt) {
      f32x4 v = acc1[nt2][mt];
#pragma unroll
      for (int rj = 0; rj < 4; ++rj) {
        int o = mt * 16 + quad * 4 + rj;
        float f = v[rj] + b1[o];
        f = fmaxf(f, 0.01f * f);
        f1base[px * 136 + o] = f2bf(f);
      }
    }
  }
  __syncthreads();

  bf16x8 a2[4][4];
#pragma unroll
  for (int mt2 = 0; mt2 < 4; ++mt2)
#pragma unroll
    for (int kt2 = 0; kt2 < 4; ++kt2)
      a2[mt2][kt2] = *(const bf16x8*)(w2l + ((mt2 * 4 + kt2) * 64 + lane) * 8);
  bf16x8 bf2[2][4];
#pragma unroll
  for (int nt2 = 0; nt2 < 2; ++nt2) {
    int px = (wv * 2 + nt2) * 16 + ln15;
#pragma unroll
    for (int kt2 = 0; kt2 < 4; ++kt2)
      bf2[nt2][kt2] =
          *(const bf16x8*)(f1base + px * 136 + kt2 * 32 + quad * 8);
  }
  f32x4 acc2[2][4];
#pragma unroll
  for (int nt2 = 0; nt2 < 2; ++nt2)
#pragma unroll
    for (int mt2 = 0; mt2 < 4; ++mt2)
      acc2[nt2][mt2] = (f32x4){0.f, 0.f, 0.f, 0.f};
#pragma unroll
  for (int mt2 = 0; mt2 < 4; ++mt2)
#pragma unroll
    for (int kt2 = 0; kt2 < 4; ++kt2)
#pragma unroll
      for (int nt2 = 0; nt2 < 2; ++nt2)
        acc2[nt2][mt2] = __builtin_amdgcn_mfma_f32_16x16x32_bf16(
            a2[mt2][kt2], bf2[nt2][kt2], acc2[nt2][mt2], 0, 0, 0);

  float s = 0.f, q = 0.f;
#pragma unroll
  for (int nt2 = 0; nt2 < 2; ++nt2) {
    int gp = p0 + (wv * 2 + nt2) * 16 + ln15;
#pragma unroll
    for (int mt2 = 0; mt2 < 4; ++mt2) {
#pragma unroll
      for (int rj = 0; rj < 4; ++rj) {
        int c = mt2 * 16 + quad * 4 + rj;
        size_t gi = (((size_t)l * 64 + c) << 14) + gp;
        float xn = x[gi] + acc2[nt2][mt2][rj] + b2[c];
        x[gi] = xn;
        s += xn;
        q = fmaf(xn, xn, q);
      }
    }
  }
#pragma unroll
  for (int off = 32; off > 0; off >>= 1) {
    s += __shfl_down(s, off); q += __shfl_down(q, off);
  }
  if (lane == 0) {
    atomicAdd(&acc[l * 2], s);
    atomicAdd(&acc[l * 2 + 1], q);
  }
}

extern "C" void kernel_launch(void* const* d_in, const int* in_sizes, int n_in,
                              void* d_out, int out_size, void* d_ws,
                              size_t ws_size, hipStream_t stream) {
  const float* x_in = (const float*)d_in[0];
  const float* ln1_g = (const float*)d_in[1];
  const float* ln1_b = (const float*)d_in[2];
  const float* Wk = (const float*)d_in[5];
  const float* Wv = (const float*)d_in[7];
  const float* bv = (const float*)d_in[8];
  const float* Wa = (const float*)d_in[9];
  const float* ln2_g = (const float*)d_in[11];
  const float* ln2_b = (const float*)d_in[12];
  const float* W1 = (const float*)d_in[13];
  const float* b1 = (const float*)d_in[14];
  const float* W2 = (const float*)d_in[15];
  const float* b2 = (const float*)d_in[16];

  float* xbuf = (float*)d_out;
  float* ws = (float*)d_ws;
  u16* Vb = (u16*)ws;                    // 16777216 u16 = 8388608 fl
  float* T = ws + 8388608;               // 6553600
  float* attn = ws + 15142208;           // 1048576
  float* Bbuf = ws + 16190784;           // 262144
  u16* w1pk = (u16*)(ws + 16452928);     // 32768 u16
  u16* w2pk = (u16*)(ws + 16469312);     // 32768 u16
  u16* wvpk = (u16*)(ws + 16485696);     // 16384 u16
  u16* wepk = (u16*)(ws + 16493888);     // 8192 u16
  float* accA = ws + 16498048;           // 32
  float* accB = ws + 16498080;           // 32
  float* mur1 = ws + 16498112;           // 32
  float* mur2 = ws + 16498144;           // 32

  hipMemsetAsync(accA, 0, 256, stream);  // accA + accB
  prep_kernel<<<4, 256, 0, stream>>>(Wa, Wk, Wv, W1, W2, w1pk, w2pk, wvpk,
                                     wepk);
  copystats_kernel<<<4096, 256, 0, stream>>>(x_in, xbuf, accA);
  sfinal_kernel<<<1, 64, 0, stream>>>(accA, mur1, accB);

  for (int d = 0; d < 4; ++d) {
    vb_kernel<<<dim3(128, 16), 256, 0, stream>>>(
        xbuf, ln1_g + (size_t)d * CHW, ln1_b + (size_t)d * CHW,
        wvpk + d * 4096, bv + d * 64, wepk + d * 2048, mur1, Vb, T);
    bconv_kernel<<<1024, 256, 0, stream>>>(T, Bbuf);
    attnc_kernel<<<4096, 256, 0, stream>>>(Vb, Bbuf, attn);
    update_stats_kernel<<<4096, 256, 0, stream>>>(xbuf, attn, accB);
    sfinal_kernel<<<1, 64, 0, stream>>>(accB, mur2, accA);
    ffn_kernel<<<2048, 256, 0, stream>>>(
        xbuf, ln2_g + (size_t)d * CHW, ln2_b + (size_t)d * CHW,
        w1pk + d * 8192, b1 + d * 128, w2pk + d * 8192, b2 + d * 64, mur2,
        accA);
    sfinal_kernel<<<1, 64, 0, stream>>>(accA, mur1, accB);
  }
}

// Round 4
// 1360.603 us; speedup vs baseline: 4.5968x; 1.2668x over previous
//
#include <hip/hip_runtime.h>

// Encoder: D=4, L=16, C=64, H=W=128.
// Math: softmax_j(A_i+B_j+ba)==softmax_j(B_j) (Q/Wq/bq/ba/bk drop out);
// attn identical for all frames i; B = conv5(h,Weff) done as GEMM into 25
// tap planes T + shift-add. Round 3: swizzled LDS everywhere (r3 ffn had
// 8.8M bank conflicts), transposed GEMM outputs (D[px][*]) for float4/
// ushort4 epilogues, sfinal inlined, attnc+update fused. 19 dispatches.

#define HW 16384
#define CHW 1048576
#define LCHW 16777216

typedef unsigned short u16;
typedef __attribute__((ext_vector_type(8))) short bf16x8;
typedef __attribute__((ext_vector_type(4))) float f32x4;

static __device__ __forceinline__ u16 f2bf(float f) {
  union { float f; unsigned int u; } v; v.f = f;
  unsigned int r = v.u + 0x7fffu + ((v.u >> 16) & 1u);
  return (u16)(r >> 16);
}
static __device__ __forceinline__ float bf2f(u16 h) {
  union { unsigned int u; float f; } v; v.u = ((unsigned int)h) << 16;
  return v.f;
}
// inline LN stats from raw accumulator
static __device__ __forceinline__ void ln_from_acc(const float* acc, int l,
                                                   float& mu, float& r) {
  const float invN = 1.f / 1048576.f;
  float s = acc[2 * l], q = acc[2 * l + 1];
  mu = s * invN;
  r = rsqrtf(q * invN - mu * mu + 1e-5f);
}

// ---- precompute bf16 MFMA fragment packs (layout identical for A/B use):
// pack[((t0*KT+kt)*64+lane)*8+j] = W[m=t0*16+(lane&15)][k=kt*32+(lane>>4)*8+j]
__global__ __launch_bounds__(256) void prep_kernel(
    const float* __restrict__ Wa, const float* __restrict__ Wk,
    const float* __restrict__ Wv, const float* __restrict__ W1,
    const float* __restrict__ W2, u16* __restrict__ w1pk,
    u16* __restrict__ w2pk, u16* __restrict__ wvpk, u16* __restrict__ wepk) {
  int d = blockIdx.x, t = threadIdx.x;
  const float* WaK = Wa + ((size_t)d * 128 + 64) * 25;
  const float* Wkd = Wk + d * 4096;
  for (int idx = t; idx < 2048; idx += 256) {  // Weff: m=tap(32), k=ci(64)
    int frag = idx >> 9, lane = (idx >> 3) & 63, j = idx & 7;
    int mt = frag >> 1, kt = frag & 1;
    int tap = mt * 16 + (lane & 15);
    int ci = kt * 32 + (lane >> 4) * 8 + j;
    float s = 0.f;
    if (tap < 25)
      for (int co = 0; co < 64; ++co)
        s = fmaf(WaK[co * 25 + tap], Wkd[co * 64 + ci], s);
    wepk[d * 2048 + idx] = f2bf(s);
  }
  const float* Wvd = Wv + d * 4096;
  for (int idx = t; idx < 4096; idx += 256) {  // Wv: m=co(64), k=ci(64)
    int frag = idx >> 9, lane = (idx >> 3) & 63, j = idx & 7;
    int mt = frag >> 1, kt = frag & 1;
    int co = mt * 16 + (lane & 15);
    int ci = kt * 32 + (lane >> 4) * 8 + j;
    wvpk[d * 4096 + idx] = f2bf(Wvd[co * 64 + ci]);
  }
  const float* W1d = W1 + d * 8192;
  for (int idx = t; idx < 8192; idx += 256) {  // W1: m=o(128), k=ci(64)
    int frag = idx >> 9, lane = (idx >> 3) & 63, j = idx & 7;
    int mt = frag >> 1, kt = frag & 1;
    int o = mt * 16 + (lane & 15);
    int ci = kt * 32 + (lane >> 4) * 8 + j;
    w1pk[d * 8192 + idx] = f2bf(W1d[o * 64 + ci]);
  }
  const float* W2d = W2 + d * 8192;
  for (int idx = t; idx < 8192; idx += 256) {  // W2: m=c(64), k=o(128)
    int frag = idx >> 9, lane = (idx >> 3) & 63, j = idx & 7;
    int mt2 = frag >> 2, kt2 = frag & 3;
    int c = mt2 * 16 + (lane & 15);
    int o = kt2 * 32 + (lane >> 4) * 8 + j;
    w2pk[d * 8192 + idx] = f2bf(W2d[c * 128 + o]);
  }
}

// ---- copy x_in -> xbuf and accumulate per-frame stats ----
__global__ __launch_bounds__(256) void copystats_kernel(
    const float* __restrict__ xin, float* __restrict__ xout,
    float* __restrict__ acc) {
  int tid = threadIdx.x;
  size_t base = (size_t)blockIdx.x * 4096;
  const float4* in4 = (const float4*)(xin + base);
  float4* out4 = (float4*)(xout + base);
  float s = 0.f, q = 0.f;
#pragma unroll
  for (int k = 0; k < 4; ++k) {
    float4 v = in4[k * 256 + tid];
    out4[k * 256 + tid] = v;
    s += v.x + v.y + v.z + v.w;
    q = fmaf(v.x, v.x, q); q = fmaf(v.y, v.y, q);
    q = fmaf(v.z, v.z, q); q = fmaf(v.w, v.w, q);
  }
#pragma unroll
  for (int off = 32; off > 0; off >>= 1) {
    s += __shfl_down(s, off); q += __shfl_down(q, off);
  }
  __shared__ float ls[4], lq[4];
  int wave = tid >> 6;
  if ((tid & 63) == 0) { ls[wave] = s; lq[wave] = q; }
  __syncthreads();
  if (tid == 0) {
    int frame = blockIdx.x >> 8;
    atomicAdd(&acc[frame * 2], ls[0] + ls[1] + ls[2] + ls[3]);
    atomicAdd(&acc[frame * 2 + 1], lq[0] + lq[1] + lq[2] + lq[3]);
  }
}

// ---- fused LN1 + V GEMM + T GEMM, transposed outputs D[px][*] ----
// LDS: h[128][72] u16 swizzled (18432) | wv pack 8KB | we pack 4KB.
__global__ __launch_bounds__(256) void vb_kernel(
    const float* __restrict__ x, const float* __restrict__ g,
    const float* __restrict__ bln, const u16* __restrict__ wvp_g,
    const float* __restrict__ bv, const u16* __restrict__ wep_g,
    const float* __restrict__ accA, float* __restrict__ accBz,
    u16* __restrict__ Vb, float* __restrict__ T) {
  __shared__ __align__(16) char lds[30720];
  u16* hb = (u16*)lds;
  u16* wvl = (u16*)(lds + 18432);
  u16* wel = (u16*)(lds + 26624);
  int tid = threadIdx.x;
  int l = blockIdx.y;
  int p0 = blockIdx.x << 7;
  // zero accB for attnc_update (safe: no other kernel concurrent)
  if (blockIdx.x == 0 && blockIdx.y == 0 && tid < 32) accBz[tid] = 0.f;
  float mu, r;
  ln_from_acc(accA, l, mu, r);

  const uint4* wv4 = (const uint4*)wvp_g;
  const uint4* we4 = (const uint4*)wep_g;
  ((uint4*)wvl)[tid] = wv4[tid];
  ((uint4*)wvl)[tid + 256] = wv4[tid + 256];
  ((uint4*)wel)[tid] = we4[tid];

  // stage h[px][ci] bf16, XOR-swizzled b64 writes (zero-conflict pattern)
#pragma unroll
  for (int it = 0; it < 2; ++it) {
    int pq = tid & 31, cg = (tid >> 5) + it * 8;
    int px = pq * 4, c0 = cg * 4;
    float vv[4][4];
#pragma unroll
    for (int i = 0; i < 4; ++i) {
      int c = c0 + i;
      size_t gi = (((size_t)l * 64 + c) << 14) + p0 + px;
      int li = (c << 14) + p0 + px;
      float4 xv = *(const float4*)(x + gi);
      float4 gv = *(const float4*)(g + li);
      float4 bb = *(const float4*)(bln + li);
      vv[i][0] = (xv.x - mu) * r * gv.x + bb.x;
      vv[i][1] = (xv.y - mu) * r * gv.y + bb.y;
      vv[i][2] = (xv.z - mu) * r * gv.z + bb.z;
      vv[i][3] = (xv.w - mu) * r * gv.w + bb.w;
    }
#pragma unroll
    for (int k = 0; k < 4; ++k) {
      int row = px + k;
      int col = c0 ^ ((row & 7) * 8);
      ushort4 hv;
      hv.x = f2bf(vv[0][k]); hv.y = f2bf(vv[1][k]);
      hv.z = f2bf(vv[2][k]); hv.w = f2bf(vv[3][k]);
      *(ushort4*)(hb + row * 72 + col) = hv;
    }
  }
  __syncthreads();

  int wv = tid >> 6, lane = tid & 63;
  int ln15 = lane & 15, quad = lane >> 4;

  // A = h rows (m=px), B = weight packs (n=co / n=tap)
  bf16x8 ah[2][2];
#pragma unroll
  for (int mt = 0; mt < 2; ++mt) {
    int px = (wv * 2 + mt) * 16 + ln15;
    int swz = (px & 7) * 8;
#pragma unroll
    for (int kt = 0; kt < 2; ++kt)
      ah[mt][kt] = *(const bf16x8*)(hb + px * 72 + ((kt * 32 + quad * 8) ^ swz));
  }
  bf16x8 bwv[4][2], bwe[2][2];
#pragma unroll
  for (int nt = 0; nt < 4; ++nt)
#pragma unroll
    for (int kt = 0; kt < 2; ++kt)
      bwv[nt][kt] = *(const bf16x8*)(wvl + ((nt * 2 + kt) * 64 + lane) * 8);
#pragma unroll
  for (int nt = 0; nt < 2; ++nt)
#pragma unroll
    for (int kt = 0; kt < 2; ++kt)
      bwe[nt][kt] = *(const bf16x8*)(wel + ((nt * 2 + kt) * 64 + lane) * 8);

  f32x4 accV[2][4], accT[2][2];
#pragma unroll
  for (int mt = 0; mt < 2; ++mt) {
#pragma unroll
    for (int nt = 0; nt < 4; ++nt) accV[mt][nt] = (f32x4){0.f, 0.f, 0.f, 0.f};
#pragma unroll
    for (int nt = 0; nt < 2; ++nt) accT[mt][nt] = (f32x4){0.f, 0.f, 0.f, 0.f};
  }
#pragma unroll
  for (int mt = 0; mt < 2; ++mt)
#pragma unroll
    for (int kt = 0; kt < 2; ++kt) {
#pragma unroll
      for (int nt = 0; nt < 4; ++nt)
        accV[mt][nt] = __builtin_amdgcn_mfma_f32_16x16x32_bf16(
            ah[mt][kt], bwv[nt][kt], accV[mt][nt], 0, 0, 0);
#pragma unroll
      for (int nt = 0; nt < 2; ++nt)
        accT[mt][nt] = __builtin_amdgcn_mfma_f32_16x16x32_bf16(
            ah[mt][kt], bwe[nt][kt], accT[mt][nt], 0, 0, 0);
    }

  // epilogue: D rows = px (quad*4+rj) -> ushort4 / float4 stores
#pragma unroll
  for (int mt = 0; mt < 2; ++mt) {
    int pxb = p0 + (wv * 2 + mt) * 16 + quad * 4;
#pragma unroll
    for (int nt = 0; nt < 4; ++nt) {
      int c = nt * 16 + ln15;
      float bvc = bv[c];
      ushort4 o;
      o.x = f2bf(accV[mt][nt][0] + bvc);
      o.y = f2bf(accV[mt][nt][1] + bvc);
      o.z = f2bf(accV[mt][nt][2] + bvc);
      o.w = f2bf(accV[mt][nt][3] + bvc);
      *(ushort4*)(Vb + (((size_t)l * 64 + c) << 14) + pxb) = o;
    }
#pragma unroll
    for (int nt = 0; nt < 2; ++nt) {
      int tap = nt * 16 + ln15;
      if (tap < 25) {
        float4 o = {accT[mt][nt][0], accT[mt][nt][1], accT[mt][nt][2],
                    accT[mt][nt][3]};
        *(float4*)(T + (((size_t)l * 25 + tap) << 14) + pxb) = o;
      }
    }
  }
}

// ---- B[l][p] = sum_tap T[l][tap][p + off(tap)] ----
__global__ __launch_bounds__(256) void bconv_kernel(
    const float* __restrict__ T, float* __restrict__ B) {
  int gid = blockIdx.x * 256 + threadIdx.x;
  int l = gid >> 14, p = gid & 16383;
  int y = p >> 7, xx = p & 127;
  float s = 0.f;
#pragma unroll
  for (int dy = 0; dy < 5; ++dy) {
    int yy = y + dy - 2;
    if (yy < 0 || yy > 127) continue;
#pragma unroll
    for (int dx = 0; dx < 5; ++dx) {
      int xc = xx + dx - 2;
      if (xc < 0 || xc > 127) continue;
      s += T[(((size_t)l * 25 + dy * 5 + dx) << 14) + (yy << 7) + xc];
    }
  }
  B[gid] = s;
}

// ---- fused: softmax over j, attnc, broadcast x+=, per-frame stats ----
// thread: 4 px (float4) of one channel c. grid 1024x256.
__global__ __launch_bounds__(256) void attnc_update_kernel(
    float* __restrict__ x, const u16* __restrict__ Vb,
    const float* __restrict__ B, float* __restrict__ accB,
    float* __restrict__ accAz) {
  int tid = threadIdx.x;
  if (blockIdx.x == 0 && tid < 32) accAz[tid] = 0.f;  // zero accA for ffn
  int gid = blockIdx.x * 256 + tid;
  int c = gid >> 12;
  int p4 = (gid & 4095) << 2;
  float4 bj[16];
  float4 m = {-1e30f, -1e30f, -1e30f, -1e30f};
#pragma unroll
  for (int j = 0; j < 16; ++j) {
    bj[j] = *(const float4*)(B + (j << 14) + p4);
    m.x = fmaxf(m.x, bj[j].x); m.y = fmaxf(m.y, bj[j].y);
    m.z = fmaxf(m.z, bj[j].z); m.w = fmaxf(m.w, bj[j].w);
  }
  float4 sum = {0.f, 0.f, 0.f, 0.f};
#pragma unroll
  for (int j = 0; j < 16; ++j) {
    bj[j].x = __expf(bj[j].x - m.x); bj[j].y = __expf(bj[j].y - m.y);
    bj[j].z = __expf(bj[j].z - m.z); bj[j].w = __expf(bj[j].w - m.w);
    sum.x += bj[j].x; sum.y += bj[j].y; sum.z += bj[j].z; sum.w += bj[j].w;
  }
  float4 a = {0.f, 0.f, 0.f, 0.f};
#pragma unroll
  for (int j = 0; j < 16; ++j) {
    ushort4 v = *(const ushort4*)(Vb + (((size_t)j * 64 + c) << 14) + p4);
    a.x = fmaf(bj[j].x, bf2f(v.x), a.x);
    a.y = fmaf(bj[j].y, bf2f(v.y), a.y);
    a.z = fmaf(bj[j].z, bf2f(v.z), a.z);
    a.w = fmaf(bj[j].w, bf2f(v.w), a.w);
  }
  a.x /= sum.x; a.y /= sum.y; a.z /= sum.z; a.w /= sum.w;
  // broadcast add to all 16 frames + per-frame stats
  float sf[16], qf[16];
#pragma unroll
  for (int f = 0; f < 16; ++f) {
    float4* xp = (float4*)(x + ((size_t)f << 20) + ((size_t)c << 14) + p4);
    float4 v = *xp;
    v.x += a.x; v.y += a.y; v.z += a.z; v.w += a.w;
    *xp = v;
    sf[f] = v.x + v.y + v.z + v.w;
    float q = 0.f;
    q = fmaf(v.x, v.x, q); q = fmaf(v.y, v.y, q);
    q = fmaf(v.z, v.z, q); q = fmaf(v.w, v.w, q);
    qf[f] = q;
  }
#pragma unroll
  for (int off = 32; off > 0; off >>= 1) {
#pragma unroll
    for (int f = 0; f < 16; ++f) {
      sf[f] += __shfl_down(sf[f], off);
      qf[f] += __shfl_down(qf[f], off);
    }
  }
  __shared__ float lsq[4][32];
  int wv = tid >> 6;
  if ((tid & 63) == 0) {
#pragma unroll
    for (int f = 0; f < 16; ++f) {
      lsq[wv][2 * f] = sf[f];
      lsq[wv][2 * f + 1] = qf[f];
    }
  }
  __syncthreads();
  if (tid < 32)
    atomicAdd(&accB[tid],
              lsq[0][tid] + lsq[1][tid] + lsq[2][tid] + lsq[3][tid]);
}

// ---- fused LN2 + FFN (MFMA, transposed GEMM2) + residual + stats ----
// LDS: h[128][72] swz (18432) | w1 16KB @18432 ; f1[128][128] swz overlays
// (32768) ; w2 16KB @34816. 51200 B.
__global__ __launch_bounds__(256) void ffn_kernel(
    float* __restrict__ x, const float* __restrict__ g,
    const float* __restrict__ bln, const u16* __restrict__ w1p_g,
    const float* __restrict__ b1, const u16* __restrict__ w2p_g,
    const float* __restrict__ b2, const float* __restrict__ accB,
    float* __restrict__ accA) {
  __shared__ __align__(16) char lds[51200];
  u16* hb = (u16*)lds;
  u16* w1l = (u16*)(lds + 18432);
  u16* f1 = (u16*)lds;  // stride 128, overlays hb+w1l after GEMM1
  u16* w2l = (u16*)(lds + 34816);

  int tid = threadIdx.x;
  int P0 = blockIdx.x << 7;
  int l = P0 >> 14;
  int p0 = P0 & 16383;
  float mu, r;
  ln_from_acc(accB, l, mu, r);

  const uint4* w1g4 = (const uint4*)w1p_g;
  const uint4* w2g4 = (const uint4*)w2p_g;
  for (int i = tid; i < 1024; i += 256) ((uint4*)w1l)[i] = w1g4[i];
  for (int i = tid; i < 1024; i += 256) ((uint4*)w2l)[i] = w2g4[i];

  // stage h (swizzled b64 writes)
#pragma unroll
  for (int it = 0; it < 2; ++it) {
    int pq = tid & 31, cg = (tid >> 5) + it * 8;
    int px = pq * 4, c0 = cg * 4;
    float vv[4][4];
#pragma unroll
    for (int i = 0; i < 4; ++i) {
      int c = c0 + i;
      size_t gi = (((size_t)l * 64 + c) << 14) + p0 + px;
      int li = (c << 14) + p0 + px;
      float4 xv = *(const float4*)(x + gi);
      float4 gv = *(const float4*)(g + li);
      float4 bb = *(const float4*)(bln + li);
      vv[i][0] = (xv.x - mu) * r * gv.x + bb.x;
      vv[i][1] = (xv.y - mu) * r * gv.y + bb.y;
      vv[i][2] = (xv.z - mu) * r * gv.z + bb.z;
      vv[i][3] = (xv.w - mu) * r * gv.w + bb.w;
    }
#pragma unroll
    for (int k = 0; k < 4; ++k) {
      int row = px + k;
      int col = c0 ^ ((row & 7) * 8);
      ushort4 hv;
      hv.x = f2bf(vv[0][k]); hv.y = f2bf(vv[1][k]);
      hv.z = f2bf(vv[2][k]); hv.w = f2bf(vv[3][k]);
      *(ushort4*)(hb + row * 72 + col) = hv;
    }
  }
  __syncthreads();

  int wv = tid >> 6, lane = tid & 63;
  int ln15 = lane & 15, quad = lane >> 4;

  // GEMM1: D[o=128][px], A=W1 pack, B=h (wave: px-tiles 2wv,2wv+1)
  bf16x8 a1[8][2];
#pragma unroll
  for (int mt = 0; mt < 8; ++mt)
#pragma unroll
    for (int kt = 0; kt < 2; ++kt)
      a1[mt][kt] = *(const bf16x8*)(w1l + ((mt * 2 + kt) * 64 + lane) * 8);
  bf16x8 bh[2][2];
#pragma unroll
  for (int nt = 0; nt < 2; ++nt) {
    int px = (wv * 2 + nt) * 16 + ln15;
    int swz = (px & 7) * 8;
#pragma unroll
    for (int kt = 0; kt < 2; ++kt)
      bh[nt][kt] = *(const bf16x8*)(hb + px * 72 + ((kt * 32 + quad * 8) ^ swz));
  }
  f32x4 acc1[2][8];
#pragma unroll
  for (int nt = 0; nt < 2; ++nt)
#pragma unroll
    for (int mt = 0; mt < 8; ++mt) acc1[nt][mt] = (f32x4){0.f, 0.f, 0.f, 0.f};
#pragma unroll
  for (int mt = 0; mt < 8; ++mt)
#pragma unroll
    for (int kt = 0; kt < 2; ++kt)
#pragma unroll
      for (int nt = 0; nt < 2; ++nt)
        acc1[nt][mt] = __builtin_amdgcn_mfma_f32_16x16x32_bf16(
            a1[mt][kt], bh[nt][kt], acc1[nt][mt], 0, 0, 0);
  __syncthreads();

  // bias+leaky -> f1[px][o] (stride 128, swizzled ushort4 writes)
#pragma unroll
  for (int nt = 0; nt < 2; ++nt) {
    int px = (wv * 2 + nt) * 16 + ln15;
    int swz = (px & 7) * 8;
#pragma unroll
    for (int mt = 0; mt < 8; ++mt) {
      int o0 = mt * 16 + quad * 4;
      float4 b1v = *(const float4*)(b1 + o0);
      float fv[4];
#pragma unroll
      for (int rj = 0; rj < 4; ++rj) {
        float f = acc1[nt][mt][rj] + ((const float*)&b1v)[rj];
        fv[rj] = fmaxf(f, 0.01f * f);
      }
      int col = ((o0 & ~7) ^ swz) + (o0 & 7);
      ushort4 ov;
      ov.x = f2bf(fv[0]); ov.y = f2bf(fv[1]);
      ov.z = f2bf(fv[2]); ov.w = f2bf(fv[3]);
      *(ushort4*)(f1 + px * 128 + col) = ov;
    }
  }
  __syncthreads();

  // GEMM2 transposed: D[px][c], A=f1 rows, B=W2 pack
  bf16x8 a2[2][4];
#pragma unroll
  for (int mt = 0; mt < 2; ++mt) {
    int px = (wv * 2 + mt) * 16 + ln15;
    int swz = (px & 7) * 8;
#pragma unroll
    for (int kt = 0; kt < 4; ++kt)
      a2[mt][kt] =
          *(const bf16x8*)(f1 + px * 128 + ((kt * 32 + quad * 8) ^ swz));
  }
  bf16x8 b2f[4][4];
#pragma unroll
  for (int nt = 0; nt < 4; ++nt)
#pragma unroll
    for (int kt = 0; kt < 4; ++kt)
      b2f[nt][kt] = *(const bf16x8*)(w2l + ((nt * 4 + kt) * 64 + lane) * 8);
  f32x4 acc2[2][4];
#pragma unroll
  for (int mt = 0; mt < 2; ++mt)
#pragma unroll
    for (int nt = 0; nt < 4; ++nt) acc2[mt][nt] = (f32x4){0.f, 0.f, 0.f, 0.f};
#pragma unroll
  for (int mt = 0; mt < 2; ++mt)
#pragma unroll
    for (int kt = 0; kt < 4; ++kt)
#pragma unroll
      for (int nt = 0; nt < 4; ++nt)
        acc2[mt][nt] = __builtin_amdgcn_mfma_f32_16x16x32_bf16(
            a2[mt][kt], b2f[nt][kt], acc2[mt][nt], 0, 0, 0);

  // epilogue: float4 residual r/w + stats
  float s = 0.f, q = 0.f;
#pragma unroll
  for (int mt = 0; mt < 2; ++mt) {
    int pxb = p0 + (wv * 2 + mt) * 16 + quad * 4;
#pragma unroll
    for (int nt = 0; nt < 4; ++nt) {
      int c = nt * 16 + ln15;
      float b2c = b2[c];
      float4* xp = (float4*)(x + (((size_t)l * 64 + c) << 14) + pxb);
      float4 v = *xp;
      v.x += acc2[mt][nt][0] + b2c;
      v.y += acc2[mt][nt][1] + b2c;
      v.z += acc2[mt][nt][2] + b2c;
      v.w += acc2[mt][nt][3] + b2c;
      *xp = v;
      s += v.x + v.y + v.z + v.w;
      q = fmaf(v.x, v.x, q); q = fmaf(v.y, v.y, q);
      q = fmaf(v.z, v.z, q); q = fmaf(v.w, v.w, q);
    }
  }
#pragma unroll
  for (int off = 32; off > 0; off >>= 1) {
    s += __shfl_down(s, off); q += __shfl_down(q, off);
  }
  if (lane == 0) {
    atomicAdd(&accA[l * 2], s);
    atomicAdd(&accA[l * 2 + 1], q);
  }
}

extern "C" void kernel_launch(void* const* d_in, const int* in_sizes, int n_in,
                              void* d_out, int out_size, void* d_ws,
                              size_t ws_size, hipStream_t stream) {
  const float* x_in = (const float*)d_in[0];
  const float* ln1_g = (const float*)d_in[1];
  const float* ln1_b = (const float*)d_in[2];
  const float* Wk = (const float*)d_in[5];
  const float* Wv = (const float*)d_in[7];
  const float* bv = (const float*)d_in[8];
  const float* Wa = (const float*)d_in[9];
  const float* ln2_g = (const float*)d_in[11];
  const float* ln2_b = (const float*)d_in[12];
  const float* W1 = (const float*)d_in[13];
  const float* b1 = (const float*)d_in[14];
  const float* W2 = (const float*)d_in[15];
  const float* b2 = (const float*)d_in[16];

  float* xbuf = (float*)d_out;
  float* ws = (float*)d_ws;
  u16* Vb = (u16*)ws;                  // [0, 8388608) fl
  float* T = ws + 8388608;             // 6553600
  float* Bbuf = ws + 14942208;         // 262144
  u16* w1pk = (u16*)(ws + 15204352);   // 32768 u16
  u16* w2pk = (u16*)(ws + 15220736);   // 32768 u16
  u16* wvpk = (u16*)(ws + 15237120);   // 16384 u16
  u16* wepk = (u16*)(ws + 15245312);   // 8192 u16
  float* accA = ws + 15249408;         // 32
  float* accB = ws + 15249440;         // 32

  hipMemsetAsync(accA, 0, 256, stream);  // accA + accB
  prep_kernel<<<4, 256, 0, stream>>>(Wa, Wk, Wv, W1, W2, w1pk, w2pk, wvpk,
                                     wepk);
  copystats_kernel<<<4096, 256, 0, stream>>>(x_in, xbuf, accA);

  for (int d = 0; d < 4; ++d) {
    vb_kernel<<<dim3(128, 16), 256, 0, stream>>>(
        xbuf, ln1_g + (size_t)d * CHW, ln1_b + (size_t)d * CHW,
        wvpk + d * 4096, bv + d * 64, wepk + d * 2048, accA, accB, Vb, T);
    bconv_kernel<<<1024, 256, 0, stream>>>(T, Bbuf);
    attnc_update_kernel<<<1024, 256, 0, stream>>>(xbuf, Vb, Bbuf, accB, accA);
    ffn_kernel<<<2048, 256, 0, stream>>>(
        xbuf, ln2_g + (size_t)d * CHW, ln2_b + (size_t)d * CHW,
        w1pk + d * 8192, b1 + d * 128, w2pk + d * 8192, b2 + d * 64, accB,
        accA);
  }
}